// Round 3
// baseline (643.558 us; speedup 1.0000x reference)
//
#include <hip/hip_runtime.h>
#include <hip/hip_bf16.h>

typedef unsigned short u16;
typedef unsigned int   u32;

#define KPS     39
#define DIN     78
#define DHID    195
#define NTOKTOT (256*2048)

#define S1      104     // JND/W1L row stride (13 x 16B chunks, odd -> bank spread)
#define S2      232     // HN/W2L row stride (29 x 16B chunks, odd)
#define M1T     13      // 13 x 16 = 208 rows (DHID padded)
#define K1S     3       // 3 x 32 = 96  (DIN + bias col padded)
#define M2T     5       // 5 x 16 = 80 rows (DIN padded)
#define K2S     7       // 7 x 32 = 224 (DHID + bias col padded)
#define TPI     64      // tokens per block-iteration (4 waves x 16)
#define TPB     1024    // tokens per block
#define NIT     (TPB/TPI)

#define W1L_E (208*S1)
#define W2L_E (80*S2)
#define JND_E (TPI*S1)
#define HN_E  (TPI*S2)
#define SMEM_BYTES ((W1L_E + W2L_E + JND_E + HN_E)*2 + DIN*2*4)

typedef __attribute__((ext_vector_type(8))) short short8;
typedef __attribute__((ext_vector_type(4))) float float4v;

static __device__ __forceinline__ u16 f2b(float v) {
  __hip_bfloat16 b = __float2bfloat16(v);
  return __builtin_bit_cast(u16, b);
}
static __device__ __forceinline__ float b2f(u16 u) {
  return __builtin_bit_cast(float, ((u32)u) << 16);
}

extern "C" __global__ __launch_bounds__(256, 1)
void fused_mlp_kernel(const float* __restrict__ xp,  const float* __restrict__ yp,
                      const float* __restrict__ W1p, const float* __restrict__ b1p,
                      const float* __restrict__ W2p, const float* __restrict__ b2p,
                      const float* __restrict__ a1p, const float* __restrict__ a2p,
                      const float* __restrict__ al1p,const float* __restrict__ be1p,
                      const float* __restrict__ al2p,const float* __restrict__ be2p,
                      float* __restrict__ out0, float* __restrict__ out1)
{
  extern __shared__ char smem[];
  u16*   W1L = (u16*)smem;
  u16*   W2L = W1L + W1L_E;
  u16*   JND = W2L + W2L_E;
  u16*   HN  = JND + JND_E;
  float* AB2 = (float*)(HN + HN_E);

  const int tid  = threadIdx.x;
  const int lane = tid & 63;
  const int w    = tid >> 6;
  const int c    = lane & 15;   // A m-index / B n-index / C-D col = lane&15 (verified)
  const int quad = lane >> 4;   // A/B k-block = quad*8 ; C/D row = quad*4+reg (verified)

  // ---------------- one-time per-block staging ----------------
  { u32* sm4 = (u32*)smem;
    for (int i = tid; i < (int)(SMEM_BYTES/4); i += 256) sm4[i] = 0; }
  __syncthreads();

  // W1 rows (f32 -> bf16); bias folded as K-column DIN (=78)
  for (int i = tid; i < DHID*DIN; i += 256) {
    int j = i / DIN, d = i - j*DIN;
    W1L[j*S1 + d] = f2b(W1p[i]);
  }
  if (tid < DHID) W1L[tid*S1 + DIN] = f2b(b1p[tid]);
  // W2 with alpha1 folded into columns; bias column (=DHID) = b2 + W2*beta1
  for (int i = tid; i < DIN*DHID; i += 256) {
    int d = i / DHID, j = i - d*DHID;
    W2L[d*S2 + j] = f2b(W2p[i] * al1p[j]);
  }
  if (tid < DIN) {
    float s = b2p[tid];
    for (int j = 0; j < DHID; ++j)
      s += W2p[tid*DHID + j] * be1p[j];
    W2L[tid*S2 + DHID] = f2b(s);
    AB2[2*tid+0] = al2p[tid];
    AB2[2*tid+1] = be2p[tid];
  }
  if (tid < TPI) {
    JND[tid*S1 + DIN]  = 0x3F80;   // 1.0 -> bias column GEMM1
    HN [tid*S2 + DHID] = 0x3F80;   // 1.0 -> bias column GEMM2
  }
  __syncthreads();

  const float a1v = a1p[0];
  const float a2v = a2p[0];

  const int blockTok = blockIdx.x * TPB;
  const int wr = w * 16;           // wave's token-row base in JND/HN

  #pragma unroll 1
  for (int it = 0; it < NIT; ++it) {
    const int tb = blockTok + it * TPI;

    // ---- stage joined = concat(x,y): 16 tokens x 39 f32 = 624 per wave ----
    {
      const float* xw = xp + (size_t)(tb + wr) * KPS;
      const float* yw = yp + (size_t)(tb + wr) * KPS;
      #pragma unroll
      for (int s = 0; s < 10; ++s) {
        int i = lane + s*64;
        if (i < 624) {
          int t = i / KPS, cc = i - t*KPS;
          JND[(wr + t)*S1 + cc]       = f2b(xw[i]);
          JND[(wr + t)*S1 + KPS + cc] = f2b(yw[i]);
        }
      }
    }

    // ---- GEMM1: h[j][t] = sum_k W1[j][k] * JND[t][k] (bias via k=DIN col) ----
    float4v acc1[M1T];
    #pragma unroll
    for (int m = 0; m < M1T; ++m)
      #pragma unroll
      for (int q = 0; q < 4; ++q) acc1[m][q] = 0.f;

    #pragma unroll
    for (int kt = 0; kt < K1S; ++kt) {
      const int ko = kt*32 + quad*8;
      short8 bfr = *(const short8*)&JND[(wr + c)*S1 + ko];
      #pragma unroll
      for (int m = 0; m < M1T; ++m) {
        short8 afr = *(const short8*)&W1L[(m*16 + c)*S1 + ko];
        acc1[m] = __builtin_amdgcn_mfma_f32_16x16x32_bf16(afr, bfr, acc1[m], 0, 0, 0);
      }
    }

    // ---- PReLU + LN1 over 195 (pad rows are exact 0) ----
    float sum = 0.f, ss = 0.f;
    #pragma unroll
    for (int m = 0; m < M1T; ++m)
      #pragma unroll
      for (int q = 0; q < 4; ++q) {
        float h = acc1[m][q];
        float p = fmaxf(h, 0.f) + a1v * fminf(h, 0.f);
        acc1[m][q] = p;
        sum += p;
        ss = __builtin_fmaf(p, p, ss);
      }
    sum += __shfl_xor(sum, 16, 64);
    sum += __shfl_xor(sum, 32, 64);
    ss  += __shfl_xor(ss,  16, 64);
    ss  += __shfl_xor(ss,  32, 64);
    const float mean = sum * (1.f/DHID);
    const float istd = rsqrtf(ss*(1.f/DHID) - mean*mean + 1e-5f);

    // store hn' = (p-mean)*istd (alpha1/beta1 folded into W2L); rows quad*4+reg
    {
      const int hrow = (wr + c)*S2;
      #pragma unroll
      for (int m = 0; m < M1T; ++m) {
        int jb = m*16 + quad*4;        // rows jb..jb+3, token c
        if (m < 12) {
          ushort4 pk;
          pk.x = f2b((acc1[m][0] - mean)*istd);
          pk.y = f2b((acc1[m][1] - mean)*istd);
          pk.z = f2b((acc1[m][2] - mean)*istd);
          pk.w = f2b((acc1[m][3] - mean)*istd);
          *(ushort4*)&HN[hrow + jb] = pk;
        } else if (quad == 0) {        // rows 192..194 only; never touch bias col 195
          HN[hrow + 192] = f2b((acc1[m][0] - mean)*istd);
          HN[hrow + 193] = f2b((acc1[m][1] - mean)*istd);
          HN[hrow + 194] = f2b((acc1[m][2] - mean)*istd);
        }
      }
    }

    // ---- GEMM2: h2[d][t] = sum_k W2'[d][k] * HN[t][k] ----
    float4v acc2[M2T];
    #pragma unroll
    for (int m = 0; m < M2T; ++m)
      #pragma unroll
      for (int q = 0; q < 4; ++q) acc2[m][q] = 0.f;

    #pragma unroll
    for (int kt = 0; kt < K2S; ++kt) {
      const int ko = kt*32 + quad*8;
      short8 bfr = *(const short8*)&HN[(wr + c)*S2 + ko];
      #pragma unroll
      for (int m = 0; m < M2T; ++m) {
        short8 afr = *(const short8*)&W2L[(m*16 + c)*S2 + ko];
        acc2[m] = __builtin_amdgcn_mfma_f32_16x16x32_bf16(afr, bfr, acc2[m], 0, 0, 0);
      }
    }

    // ---- PReLU + LN2 + residual + store (f32 out) ----
    float sum2 = 0.f, ss2 = 0.f;
    #pragma unroll
    for (int m = 0; m < M2T; ++m)
      #pragma unroll
      for (int q = 0; q < 4; ++q) {
        float h = acc2[m][q];
        float p = fmaxf(h, 0.f) + a2v * fminf(h, 0.f);
        acc2[m][q] = p;
        sum2 += p;
        ss2 = __builtin_fmaf(p, p, ss2);
      }
    sum2 += __shfl_xor(sum2, 16, 64);
    sum2 += __shfl_xor(sum2, 32, 64);
    ss2  += __shfl_xor(ss2,  16, 64);
    ss2  += __shfl_xor(ss2,  32, 64);
    const float mean2 = sum2 * (1.f/DIN);
    const float istd2 = rsqrtf(ss2*(1.f/DIN) - mean2*mean2 + 1e-5f);

    const int gt   = tb + wr + c;
    const int jrow = (wr + c)*S1;
    #pragma unroll
    for (int m = 0; m < M2T; ++m) {
      int d0 = m*16 + quad*4;          // rows d0..d0+3, token c
      if (d0 < DIN) {
        ushort4 res = *(const ushort4*)&JND[jrow + d0];
        u16 rr[4] = {res.x, res.y, res.z, res.w};
        #pragma unroll
        for (int r = 0; r < 4; ++r) {
          int d = d0 + r;
          if (d < DIN) {
            float2 ab = *(const float2*)&AB2[2*d];
            float  v  = (acc2[m][r] - mean2)*istd2*ab.x + ab.y + b2f(rr[r]);
            if (d < KPS) out0[(size_t)gt*KPS + d]         = v;
            else         out1[(size_t)gt*KPS + (d - KPS)] = v;
          }
        }
      }
    }
  }
}

extern "C" void kernel_launch(void* const* d_in, const int* in_sizes, int n_in,
                              void* d_out, int out_size, void* d_ws, size_t ws_size,
                              hipStream_t stream) {
  const float* xp   = (const float*)d_in[0];
  const float* yp   = (const float*)d_in[1];
  const float* W1p  = (const float*)d_in[2];
  const float* b1p  = (const float*)d_in[3];
  const float* W2p  = (const float*)d_in[4];
  const float* b2p  = (const float*)d_in[5];
  const float* a1p  = (const float*)d_in[6];
  const float* a2p  = (const float*)d_in[7];
  const float* al1p = (const float*)d_in[8];
  const float* be1p = (const float*)d_in[9];
  const float* al2p = (const float*)d_in[10];
  const float* be2p = (const float*)d_in[11];

  float* out0 = (float*)d_out;
  float* out1 = out0 + (size_t)NTOKTOT * KPS;

  hipFuncSetAttribute((const void*)fused_mlp_kernel,
                      hipFuncAttributeMaxDynamicSharedMemorySize, SMEM_BYTES);

  fused_mlp_kernel<<<NTOKTOT/TPB, 256, SMEM_BYTES, stream>>>(
      xp, yp, W1p, b1p, W2p, b2p, a1p, a2p, al1p, be1p, al2p, be2p, out0, out1);
}